// Round 13
// baseline (391.148 us; speedup 1.0000x reference)
//
#include <hip/hip_runtime.h>
#include <hip/hip_bf16.h>
#include <math.h>

// ---------------------------------------------------------------------------
// Gated causal attention block, bf16 MFMA pipeline. B=2,N=2048,DIM=2048,H=16,DH=128.
// R13: qkv GEMM rebuilt as m201-style 8-phase fine interleave (256x256, BK=64,
//     8 waves, 128KB dbuf). Per phase: {ds_reads (12@p0 / 4) | stage 1 region |
//     barrier | lgkmcnt(0) | 16 MFMA setprio-wrapped | barrier}; B cached in
//     regs across the K-tile; vmcnt(7) once per K-tile (ledger verified);
//     staging overwrites only regions read at earlier phases (race-safe by the
//     double-barrier + pre-MFMA lgkm drain). Grid 384, n-band XCD map.
//     attn / gemm_out / prologue unchanged from R12.
// ---------------------------------------------------------------------------

typedef __attribute__((ext_vector_type(8))) __bf16 bf16x8;
typedef __attribute__((ext_vector_type(4))) __bf16 bf16x4;
typedef __attribute__((ext_vector_type(4))) float f32x4;

#define MFMA_BF16(a, b, c) __builtin_amdgcn_mfma_f32_16x16x32_bf16((a), (b), (c), 0, 0, 0)

#define NB 2
#define NSEQ 2048
#define NDIM 2048
#define NH 16
#define NDH 128
#define SCALE_Q 0.08838834764831845f /* 128^-0.5 */

#define AS1 __attribute__((address_space(1)))
#define AS3 __attribute__((address_space(3)))
static __device__ __forceinline__ void gload_lds16(const void* g, void* l) {
  __builtin_amdgcn_global_load_lds((AS1 const void*)g, (AS3 void*)l, 16, 0, 0);
}

static __device__ __forceinline__ unsigned pack2_bf16(float a, float b) {
  unsigned short ua = __builtin_bit_cast(unsigned short, (__bf16)a);
  unsigned short ub = __builtin_bit_cast(unsigned short, (__bf16)b);
  return (unsigned)ua | ((unsigned)ub << 16);
}

// ---------------------------------------------------------------------------
// Fused x->bf16 conversion + gates. One block per row (b*N+n).
__global__ __launch_bounds__(256) void cvt_gates_kernel(const float* __restrict__ x,
                                                        const float* __restrict__ wg,
                                                        __bf16* __restrict__ x_bf,
                                                        float* __restrict__ gates) {
  __shared__ float red[64];
  int row = blockIdx.x;
  int tid = threadIdx.x;
  const float* xr = x + (size_t)row * NDIM;
  int k0 = tid * 8;
  float4 v0 = *reinterpret_cast<const float4*>(xr + k0);
  float4 v1 = *reinterpret_cast<const float4*>(xr + k0 + 4);
  float vv[8] = {v0.x, v0.y, v0.z, v0.w, v1.x, v1.y, v1.z, v1.w};
  union { bf16x8 v; } o;
#pragma unroll
  for (int j = 0; j < 8; ++j) o.v[j] = (__bf16)vv[j];
  *reinterpret_cast<bf16x8*>(x_bf + (size_t)row * NDIM + k0) = o.v;

  float acc[16];
#pragma unroll
  for (int h = 0; h < 16; ++h) acc[h] = 0.f;
#pragma unroll
  for (int j = 0; j < 8; ++j) {
    const float* wr = wg + (size_t)(k0 + j) * NH;
#pragma unroll
    for (int h = 0; h < 16; ++h) acc[h] += vv[j] * wr[h];
  }
  int w = tid >> 6, lane = tid & 63;
#pragma unroll
  for (int h = 0; h < 16; ++h) {
    float v = acc[h];
#pragma unroll
    for (int off = 32; off; off >>= 1) v += __shfl_down(v, off);
    if (lane == 0) red[w * 16 + h] = v;
  }
  __syncthreads();
  if (tid < 16) {
    float s = red[tid] + red[16 + tid] + red[32 + tid] + red[48 + tid];
    int b = row >> 11, n = row & 2047;
    gates[((size_t)(b * NH + tid)) * NSEQ + n] = 1.f / (1.f + expf(-s));
  }
}

// in: f32 [K][C] row-major -> out: bf16 [C][K] row-major
__global__ __launch_bounds__(256) void transpose_cvt_kernel(const float* __restrict__ in,
                                                            __bf16* __restrict__ out,
                                                            int K, int C) {
  __shared__ float tile[32][33];
  int c0 = blockIdx.x * 32, k0 = blockIdx.y * 32;
  int t = threadIdx.x;
  int lc = t & 31, lr = t >> 5;
#pragma unroll
  for (int rr = 0; rr < 4; ++rr)
    tile[lr + rr * 8][lc] = in[(size_t)(k0 + lr + rr * 8) * C + c0 + lc];
  __syncthreads();
#pragma unroll
  for (int rr = 0; rr < 4; ++rr)
    out[(size_t)(c0 + lr + rr * 8) * K + k0 + lc] = (__bf16)tile[lc][lr + rr * 8];
}

// ---------------------------------------------------------------------------
// R13 qkv: 256x256, BK=64, 8 waves (2Mx4N, wave C = 128x64), 8-phase schedule.
// LDS: SA/SB [2][256][64] bf16 = 128KB. Swizzle: granule' = gran ^ (row&7)
// (2-way = free; measured 0 conflicts), staged via pre-swizzled global source.
// A-quadrant q (rows {q*32..+31} U {128+q*32..+31}) is read exactly at phase q;
// B is read entirely at phase 0 and cached in VGPRs.
__global__ __launch_bounds__(512, 2) void gemm_qkv8p(const __bf16* __restrict__ A,
                                                     const __bf16* __restrict__ Bt,
                                                     __bf16* __restrict__ qb,
                                                     __bf16* __restrict__ kb,
                                                     __bf16* __restrict__ vtb) {
  __shared__ __align__(1024) __bf16 SA[2][256][64];
  __shared__ __align__(1024) __bf16 SB[2][256][64];
  int sblk = blockIdx.x;
  int x = sblk & 7, i = sblk >> 3;           // x: XCD, i: 0..47
  int n0 = (3 * x + (i % 3)) * 256;          // XCD owns a 768-col B band (3.1MB, L2-fit)
  int m0 = (i / 3) * 256;
  const __bf16* Ab = A + (size_t)m0 * 2048;
  const __bf16* Bb = Bt + (size_t)n0 * 2048;

  int tid = threadIdx.x;
  int w = tid >> 6, lane = tid & 63;
  int ln15 = lane & 15, g = lane >> 4;
  int wr = w >> 2, wc = w & 3;
  int l8 = lane >> 3, l7 = lane & 7;
  int sg = l7 ^ l8;  // inverse-swizzled source granule (row&7 == l8 for stages)

  // stage A quadrant q of K-tile kt into buffer bf (64 rows, 1 gload/thread).
  auto stage_aq = [&](int kt, int q, int bf) {
    int rb = (w >> 2) * 128 + q * 32 + (w & 3) * 8;  // wave-uniform row base
    int row = rb + l8;
    gload_lds16(Ab + (size_t)row * 2048 + kt * 64 + sg * 8, &SA[bf][rb][0]);
  };
  // stage B half h of K-tile kt into buffer bf (128 rows, 2 gloads/thread).
  auto stage_bh = [&](int kt, int h, int bf) {
#pragma unroll
    for (int j = 0; j < 2; ++j) {
      int rb = h * 128 + j * 64 + w * 8;
      int row = rb + l8;
      gload_lds16(Bb + (size_t)row * 2048 + kt * 64 + sg * 8, &SB[bf][rb][0]);
    }
  };

  f32x4 acc[8][4];
#pragma unroll
  for (int a = 0; a < 8; ++a)
#pragma unroll
    for (int nf = 0; nf < 4; ++nf) acc[a][nf] = (f32x4){0.f, 0.f, 0.f, 0.f};

  // prologue: tile0 complete (8 loads), tile1 all but A-Q3 (7 loads).
  stage_aq(0, 0, 0); stage_aq(0, 1, 0); stage_aq(0, 2, 0); stage_aq(0, 3, 0);
  stage_bh(0, 0, 0); stage_bh(0, 1, 0);
  stage_aq(1, 0, 1); stage_aq(1, 1, 1); stage_aq(1, 2, 1);
  stage_bh(1, 0, 1); stage_bh(1, 1, 1);
  asm volatile("s_waitcnt vmcnt(7)" ::: "memory");  // tile 0 landed (15->7)
  __builtin_amdgcn_s_barrier();

  bf16x8 bfr[4][2], af2[2][2];
  for (int t = 0; t < 32; ++t) {
    int bf = t & 1;
    const __bf16* sa = &SA[bf][0][0];
    const __bf16* sb = &SB[bf][0][0];
    int kt1 = (t + 1 < 32) ? t + 1 : 31;
    int kt2 = (t + 2 < 32) ? t + 2 : 31;
#pragma unroll
    for (int p = 0; p < 4; ++p) {
      // ---- ds reads (p0: 12, else: 4) ----
      if (p == 0) {
#pragma unroll
        for (int nf = 0; nf < 4; ++nf) {
          int r = wc * 64 + nf * 16 + ln15;
          bfr[nf][0] = *(const bf16x8*)(sb + r * 64 + ((g) ^ (r & 7)) * 8);
          bfr[nf][1] = *(const bf16x8*)(sb + r * 64 + ((4 | g) ^ (r & 7)) * 8);
        }
      }
#pragma unroll
      for (int f = 0; f < 2; ++f) {
        int r = wr * 128 + (2 * p + f) * 16 + ln15;
        af2[f][0] = *(const bf16x8*)(sa + r * 64 + ((g) ^ (r & 7)) * 8);
        af2[f][1] = *(const bf16x8*)(sa + r * 64 + ((4 | g) ^ (r & 7)) * 8);
      }
      // ---- stage (regions read at phases <= p-1 only; see race proof) ----
      if (p == 0) stage_aq(kt1, 3, bf ^ 1);                 // deferred Q3 of t+1
      if (p == 1) { stage_aq(kt2, 0, bf); stage_bh(kt2, 0, bf); }
      if (p == 2) { stage_aq(kt2, 1, bf); stage_bh(kt2, 1, bf); }
      if (p == 3) stage_aq(kt2, 2, bf);
      __builtin_amdgcn_s_barrier();
      asm volatile("s_waitcnt lgkmcnt(0)" ::: "memory");
      __builtin_amdgcn_sched_barrier(0);
      __builtin_amdgcn_s_setprio(1);
#pragma unroll
      for (int f = 0; f < 2; ++f)
#pragma unroll
        for (int nf = 0; nf < 4; ++nf) {
          acc[2 * p + f][nf] = MFMA_BF16(af2[f][0], bfr[nf][0], acc[2 * p + f][nf]);
          acc[2 * p + f][nf] = MFMA_BF16(af2[f][1], bfr[nf][1], acc[2 * p + f][nf]);
        }
      __builtin_amdgcn_s_setprio(0);
      if (p == 3)
        asm volatile("s_waitcnt vmcnt(7)" ::: "memory");  // retire tile t+1 (15->7)
      __builtin_amdgcn_s_barrier();
    }
  }
  asm volatile("s_waitcnt vmcnt(0)" ::: "memory");  // drain tail junk prefetch

  // epilogue: qkv/h/d decode, scatter q(scaled)/k/v^T
#pragma unroll
  for (int nf = 0; nf < 4; ++nf) {
    int ng = n0 + wc * 64 + nf * 16 + ln15;
    int qkv = ng >> 11;
    int h = (ng >> 7) & 15;
    int d = ng & 127;
#pragma unroll
    for (int mf = 0; mf < 8; ++mf)
#pragma unroll
      for (int rr = 0; rr < 4; ++rr) {
        int m = m0 + wr * 128 + mf * 16 + g * 4 + rr;
        int b = m >> 11, n = m & 2047;
        int bh = b * NH + h;
        float v = acc[mf][nf][rr];
        if (qkv == 0)
          qb[((size_t)bh * NSEQ + n) * NDH + d] = (__bf16)(v * SCALE_Q);
        else if (qkv == 1)
          kb[((size_t)bh * NSEQ + n) * NDH + d] = (__bf16)v;
        else
          vtb[((size_t)bh * NDH + d) * NSEQ + n] = (__bf16)v;
      }
  }
}

// ---------------------------------------------------------------------------
// gemm_out (unchanged R12): BM=256, BN=128, BK=32, ring-of-6, vmcnt(12).
struct SmemO {
  __bf16 T[6][384][32];  // 144 KiB
};

static __device__ __forceinline__ const bf16x8* fragq(const __bf16* base, int row, int g) {
  return (const bf16x8*)(base + row * 32 + (g ^ ((row >> 1) & 3)) * 8);
}

__global__ __launch_bounds__(512, 2) void gemm_out256r(const __bf16* __restrict__ A,
                                                       const __bf16* __restrict__ Bt,
                                                       float* __restrict__ out) {
  __shared__ __align__(1024) SmemO S;
  int sblk = blockIdx.x;
  int x = sblk & 7, i = sblk >> 3;
  int m0 = (i >> 1) * 256;
  int n0 = (2 * x + (i & 1)) * 128;
  const __bf16* Ab = A + (size_t)m0 * 2048;
  const __bf16* Bb = Bt + (size_t)n0 * 2048;

  int tid = threadIdx.x;
  int w = tid >> 6, lane = tid & 63;
  int ln15 = lane & 15, g = lane >> 4;
  int wr = w >> 2, wc = w & 3;
  int lr4 = lane >> 2, l3 = lane & 3;

  auto stage = [&](int kt, int rb) {
#pragma unroll
    for (int j = 0; j < 3; ++j) {
      int k = w + 8 * j;
      int row = k * 16 + lr4;
      int sg = l3 ^ ((row >> 1) & 3);
      const __bf16* src = (k < 16)
          ? Ab + (size_t)row * 2048 + kt * 32 + sg * 8
          : Bb + (size_t)(row - 256) * 2048 + kt * 32 + sg * 8;
      gload_lds16(src, &S.T[rb][k * 16][0]);
    }
  };

  f32x4 acc[8][2];
#pragma unroll
  for (int a = 0; a < 8; ++a)
#pragma unroll
    for (int nf = 0; nf < 2; ++nf) acc[a][nf] = (f32x4){0.f, 0.f, 0.f, 0.f};

  stage(0, 0); stage(1, 1); stage(2, 2); stage(3, 3); stage(4, 4);
  for (int t = 0; t < 64; ++t) {
    int rb = t % 6;
    asm volatile("s_waitcnt vmcnt(12)" ::: "memory");
    __builtin_amdgcn_s_barrier();
    asm volatile("" ::: "memory");
    int ts = (t < 59) ? t + 5 : 63;
    stage(ts, (t + 5) % 6);
    const __bf16* Sb = &S.T[rb][0][0];
    bf16x8 bfr[2];
#pragma unroll
    for (int nf = 0; nf < 2; ++nf) {
      int row = 256 + wc * 32 + nf * 16 + ln15;
      bfr[nf] = *fragq(Sb, row, g);
    }
#pragma unroll
    for (int mh = 0; mh < 2; ++mh) {
      bf16x8 af[4];
#pragma unroll
      for (int a = 0; a < 4; ++a) {
        int row = wr * 128 + (mh * 4 + a) * 16 + ln15;
        af[a] = *fragq(Sb, row, g);
      }
      __builtin_amdgcn_s_setprio(1);
#pragma unroll
      for (int a = 0; a < 4; ++a)
#pragma unroll
        for (int nf = 0; nf < 2; ++nf)
          acc[mh * 4 + a][nf] = MFMA_BF16(af[a], bfr[nf], acc[mh * 4 + a][nf]);
      __builtin_amdgcn_s_setprio(0);
    }
  }
  asm volatile("s_waitcnt vmcnt(0)" ::: "memory");

#pragma unroll
  for (int mf = 0; mf < 8; ++mf)
#pragma unroll
    for (int nf = 0; nf < 2; ++nf)
#pragma unroll
      for (int rr = 0; rr < 4; ++rr) {
        int m = m0 + wr * 128 + mf * 16 + g * 4 + rr;
        int c = n0 + wc * 32 + nf * 16 + ln15;
        out[(size_t)m * NDIM + c] = acc[mf][nf][rr];
      }
}

// ---------------------------------------------------------------------------
// Flash attention (unchanged R11/R12): 256 thr / 4 waves, dual-q (lo,31-lo),
// 512 blocks = 2/CU, dbuf KV + counted vmcnt(8), fixed-max softmax, fused softcap.
static __device__ __forceinline__ void softcap_p(const f32x4* accS, float (*p)[4],
                                                 float& l_r, int j0, int q0s,
                                                 bool diag, int ln15, int g) {
#pragma unroll
  for (int jt = 0; jt < 4; ++jt)
#pragma unroll
    for (int r = 0; r < 4; ++r) {
      float e2 = __builtin_amdgcn_exp2f(accS[jt][r] * 0.057707801635558536f);
      float rc = __builtin_amdgcn_rcpf(e2 + 1.f);
      float pv = __builtin_amdgcn_exp2f(fmaf(rc, -144.26950408889634f, 54.82241155378061f));
      if (diag && (j0 + jt * 16 + g * 4 + r > q0s + ln15)) pv = 0.f;
      p[jt][r] = pv;
      l_r += pv;
    }
}

static __device__ __forceinline__ bf16x8 build_pa(const float (*p)[4], int c,
                                                  int lane_lo, int lane_hi, int g) {
  unsigned P0w0 = pack2_bf16(p[2 * c][0], p[2 * c][1]);
  unsigned P0w1 = pack2_bf16(p[2 * c][2], p[2 * c][3]);
  unsigned P1w0 = pack2_bf16(p[2 * c + 1][0], p[2 * c + 1][1]);
  unsigned P1w1 = pack2_bf16(p[2 * c + 1][2], p[2 * c + 1][3]);
  unsigned a0 = (unsigned)__shfl((int)P0w0, lane_lo);
  unsigned a1 = (unsigned)__shfl((int)P0w1, lane_lo);
  unsigned b0 = (unsigned)__shfl((int)P1w0, lane_lo);
  unsigned b1 = (unsigned)__shfl((int)P1w1, lane_lo);
  unsigned c0 = (unsigned)__shfl((int)P0w0, lane_hi);
  unsigned c1 = (unsigned)__shfl((int)P0w1, lane_hi);
  unsigned e0 = (unsigned)__shfl((int)P1w0, lane_hi);
  unsigned e1 = (unsigned)__shfl((int)P1w1, lane_hi);
  union { unsigned u[4]; bf16x8 v; } pu;
  pu.u[0] = (g < 2) ? a0 : b0;
  pu.u[1] = (g < 2) ? a1 : b1;
  pu.u[2] = (g < 2) ? c0 : e0;
  pu.u[3] = (g < 2) ? c1 : e1;
  return pu.v;
}

static __device__ __forceinline__ void attn_tile2(const __bf16* __restrict__ Kl,
                                                  const __bf16* __restrict__ Vl,
                                                  const bf16x8* qfh, const bf16x8* qfl,
                                                  f32x4* acc_h, f32x4* acc_l,
                                                  float& l_h, float& l_l,
                                                  int j0, int q0h, int q0l,
                                                  bool diag_h, bool diag_l, bool do_lo,
                                                  int ln15, int g) {
  f32x4 sh[4], sl[4];
#pragma unroll
  for (int jt = 0; jt < 4; ++jt) {
    sh[jt] = (f32x4){0.f, 0.f, 0.f, 0.f};
    sl[jt] = (f32x4){0.f, 0.f, 0.f, 0.f};
  }
  __builtin_amdgcn_s_setprio(1);
#pragma unroll
  for (int jt = 0; jt < 4; ++jt)
#pragma unroll
    for (int kc = 0; kc < 4; ++kc) {
      int row = jt * 16 + ln15;
      int bc = (kc * 64 + g * 16) ^ ((row & 7) << 4);
      bf16x8 kf = *reinterpret_cast<const bf16x8*>(Kl + row * 128 + (bc >> 1));
      sh[jt] = MFMA_BF16(kf, qfh[kc], sh[jt]);
      if (do_lo) sl[jt] = MFMA_BF16(kf, qfl[kc], sl[jt]);
    }
  __builtin_amdgcn_s_setprio(0);
  float ph[4][4], pl[4][4];
  softcap_p(sh, ph, l_h, j0, q0h, diag_h, ln15, g);
  if (do_lo) softcap_p(sl, pl, l_l, j0, q0l, diag_l, ln15, g);
  int lane_lo = ln15 + 32 * (g & 1);
  int lane_hi = lane_lo + 16;
#pragma unroll
  for (int c = 0; c < 2; ++c) {
    bf16x8 pah = build_pa(ph, c, lane_lo, lane_hi, g);
    bf16x8 pal = build_pa(pl, c, lane_lo, lane_hi, g);
    __builtin_amdgcn_s_setprio(1);
#pragma unroll
    for (int d0 = 0; d0 < 8; ++d0) {
      int d = d0 * 16 + ln15;
      int bc = (c * 64 + g * 16) ^ ((d & 7) << 4);
      bf16x8 vf = *reinterpret_cast<const bf16x8*>(Vl + d * 64 + (bc >> 1));
      acc_h[d0] = MFMA_BF16(pah, vf, acc_h[d0]);
      if (do_lo) acc_l[d0] = MFMA_BF16(pal, vf, acc_l[d0]);
    }
    __builtin_amdgcn_s_setprio(0);
  }
}

__global__ __launch_bounds__(256, 2) void attn_kernel(const __bf16* __restrict__ qb,
                                                      const __bf16* __restrict__ kb,
                                                      const __bf16* __restrict__ vtb,
                                                      const float* __restrict__ gates,
                                                      __bf16* __restrict__ og) {
  __shared__ __align__(1024) __bf16 Kl[2][64 * 128];
  __shared__ __align__(1024) __bf16 Vl[2][128 * 64];
  int tid = threadIdx.x;
  int w = tid >> 6, lane = tid & 63;
  int ln15 = lane & 15, g = lane >> 4;
  int bx = blockIdx.x;
  int lo = bx & 15, bh = bx >> 4;
  int hi = 31 - lo;
  const __bf16* qh = qb + (size_t)bh * NSEQ * NDH;
  const __bf16* kh = kb + (size_t)bh * NSEQ * NDH;
  const __bf16* vh = vtb + (size_t)bh * NDH * NSEQ;

  int q0h = hi * 64 + w * 16;
  int q0l = lo * 64 + w * 16;
  bf16x8 qfh[4], qfl[4];
#pragma unroll
  for (int kc = 0; kc < 4; ++kc) {
    qfh[kc] = *reinterpret_cast<const bf16x8*>(qh + (size_t)(q0h + ln15) * NDH + kc * 32 + g * 8);
    qfl[kc] = *reinterpret_cast<const bf16x8*>(qh + (size_t)(q0l + ln15) * NDH + kc * 32 + g * 8);
  }

  f32x4 acc_h[8], acc_l[8];
#pragma unroll
  for (int d0 = 0; d0 < 8; ++d0) {
    acc_h[d0] = (f32x4){0.f, 0.f, 0.f, 0.f};
    acc_l[d0] = (f32x4){0.f, 0.f, 0.f, 0.f};
  }
  float l_h = 0.f, l_l = 0.f;

  auto stage = [&](int t, int buf) {
    int j0 = t * 64;
#pragma unroll
    for (int i = 0; i < 4; ++i) {
      int gi = (i * 4 + w) * 64 + lane;
      int kr = gi >> 4, kcs = gi & 15;
      int kc_ = kcs ^ (kr & 7);
      gload_lds16(kh + (size_t)(j0 + kr) * NDH + kc_ * 8, &Kl[buf][(i * 4 + w) * 512]);
      int vr = gi >> 3, vcs = gi & 7;
      int vc_ = vcs ^ (vr & 7);
      gload_lds16(vh + (size_t)vr * NSEQ + j0 + vc_ * 8, &Vl[buf][(i * 4 + w) * 512]);
    }
  };

  stage(0, 0);
  for (int t = 0; t <= hi; ++t) {
    int cb = t & 1;
    if (t < hi) {
      stage(t + 1, cb ^ 1);
      asm volatile("s_waitcnt vmcnt(8)" ::: "memory");
    } else {
      asm volatile("s_waitcnt vmcnt(0)" ::: "memory");
    }
    __builtin_amdgcn_s_barrier();
    attn_tile2(&Kl[cb][0], &Vl[cb][0], qfh, qfl, acc_h, acc_l, l_h, l_l,
               t * 64, q0h, q0l, t == hi, t == lo, t <= lo, ln15, g);
    __builtin_amdgcn_s_barrier();
  }

  l_h += __shfl_xor(l_h, 16); l_h += __shfl_xor(l_h, 32);
  l_l += __shfl_xor(l_l, 16); l_l += __shfl_xor(l_l, 32);

  int b = bh >> 4, h = bh & 15;
#pragma unroll
  for (int set = 0; set < 2; ++set) {
    int q0s = set ? q0l : q0h;
    f32x4* acc = set ? acc_l : acc_h;
    float lr = set ? l_l : l_h;
    float gv[4];
#pragma unroll
    for (int r = 0; r < 4; ++r) {
      float lv = __shfl(lr, g * 4 + r);
      int row = q0s + g * 4 + r;
      gv[r] = gates[(size_t)bh * NSEQ + row] / lv;
    }
#pragma unroll
    for (int d0 = 0; d0 < 8; ++d0)
#pragma unroll
      for (int r = 0; r < 4; ++r) {
        int row = q0s + g * 4 + r;
        og[((size_t)(b * NSEQ + row)) * NDIM + h * NDH + d0 * 16 + ln15] =
            (__bf16)(acc[d0][r] * gv[r]);
      }
  }
}

// ---------------------------------------------------------------------------
extern "C" void kernel_launch(void* const* d_in, const int* in_sizes, int n_in,
                              void* d_out, int out_size, void* d_ws, size_t ws_size,
                              hipStream_t stream) {
  const float* x = (const float*)d_in[0];
  const float* w_qkv = (const float*)d_in[1];
  const float* w_gates = (const float*)d_in[2];
  const float* w_out = (const float*)d_in[3];
  float* out = (float*)d_out;
  char* ws = (char*)d_ws;

  __bf16* x_bf   = (__bf16*)(ws + 0);          // 16,777,216
  __bf16* wqkv_t = (__bf16*)(ws + 16777216);   // 25,165,824
  __bf16* wout_t = (__bf16*)(ws + 41943040);   // 8,388,608
  __bf16* q_buf  = (__bf16*)(ws + 50331648);   // 16,777,216
  __bf16* k_buf  = (__bf16*)(ws + 67108864);   // 16,777,216
  __bf16* vt_buf = (__bf16*)(ws + 83886080);   // 16,777,216
  float*  gates  = (float*)(ws + 100663296);   // 262,144
  __bf16* attn_g = (__bf16*)(ws + 100925440);  // 16,777,216

  cvt_gates_kernel<<<4096, 256, 0, stream>>>(x, w_gates, x_bf, gates);
  transpose_cvt_kernel<<<dim3(192, 64), 256, 0, stream>>>(w_qkv, wqkv_t, 2048, 6144);
  transpose_cvt_kernel<<<dim3(64, 64), 256, 0, stream>>>(w_out, wout_t, 2048, 2048);
  gemm_qkv8p<<<384, 512, 0, stream>>>(x_bf, wqkv_t, q_buf, k_buf, vt_buf);
  attn_kernel<<<512, 256, 0, stream>>>(q_buf, k_buf, vt_buf, gates, attn_g);
  gemm_out256r<<<256, 512, 0, stream>>>(attn_g, wout_t, out);
}

// Round 16
// 340.893 us; speedup vs baseline: 1.1474x; 1.1474x over previous
//
#include <hip/hip_runtime.h>
#include <hip/hip_bf16.h>
#include <math.h>

// ---------------------------------------------------------------------------
// Gated causal attention block, bf16 MFMA pipeline. B=2,N=2048,DIM=2048,H=16,DH=128.
// R16: R15's 2-phase qkv with the RACE FIXED. R15's nan: bottom-of-loop
//     vmcnt(10) was a no-op (only 10 loads outstanding: tiles t+1,t+2), so
//     tile t+1 was read unlanded; and the prologue had no wait before tile 0
//     was read. Fix: prologue vmcnt(5)+barrier (tile 0 landed block-wide),
//     bottom wait vmcnt(5) (retires exactly tile t+1). Ledger re-derived:
//     entry invariant = tiles<=t landed, t+1 in flight(5), t+2 unissued.
//     gemm_out / attn / prologue unchanged from R12.
// ---------------------------------------------------------------------------

typedef __attribute__((ext_vector_type(8))) __bf16 bf16x8;
typedef __attribute__((ext_vector_type(4))) __bf16 bf16x4;
typedef __attribute__((ext_vector_type(4))) float f32x4;

#define MFMA_BF16(a, b, c) __builtin_amdgcn_mfma_f32_16x16x32_bf16((a), (b), (c), 0, 0, 0)

#define NB 2
#define NSEQ 2048
#define NDIM 2048
#define NH 16
#define NDH 128
#define SCALE_Q 0.08838834764831845f /* 128^-0.5 */

#define AS1 __attribute__((address_space(1)))
#define AS3 __attribute__((address_space(3)))
static __device__ __forceinline__ void gload_lds16(const void* g, void* l) {
  __builtin_amdgcn_global_load_lds((AS1 const void*)g, (AS3 void*)l, 16, 0, 0);
}

static __device__ __forceinline__ unsigned pack2_bf16(float a, float b) {
  unsigned short ua = __builtin_bit_cast(unsigned short, (__bf16)a);
  unsigned short ub = __builtin_bit_cast(unsigned short, (__bf16)b);
  return (unsigned)ua | ((unsigned)ub << 16);
}

// ---------------------------------------------------------------------------
// Fused x->bf16 conversion + gates. One block per row (b*N+n).
__global__ __launch_bounds__(256) void cvt_gates_kernel(const float* __restrict__ x,
                                                        const float* __restrict__ wg,
                                                        __bf16* __restrict__ x_bf,
                                                        float* __restrict__ gates) {
  __shared__ float red[64];
  int row = blockIdx.x;
  int tid = threadIdx.x;
  const float* xr = x + (size_t)row * NDIM;
  int k0 = tid * 8;
  float4 v0 = *reinterpret_cast<const float4*>(xr + k0);
  float4 v1 = *reinterpret_cast<const float4*>(xr + k0 + 4);
  float vv[8] = {v0.x, v0.y, v0.z, v0.w, v1.x, v1.y, v1.z, v1.w};
  union { bf16x8 v; } o;
#pragma unroll
  for (int j = 0; j < 8; ++j) o.v[j] = (__bf16)vv[j];
  *reinterpret_cast<bf16x8*>(x_bf + (size_t)row * NDIM + k0) = o.v;

  float acc[16];
#pragma unroll
  for (int h = 0; h < 16; ++h) acc[h] = 0.f;
#pragma unroll
  for (int j = 0; j < 8; ++j) {
    const float* wr = wg + (size_t)(k0 + j) * NH;
#pragma unroll
    for (int h = 0; h < 16; ++h) acc[h] += vv[j] * wr[h];
  }
  int w = tid >> 6, lane = tid & 63;
#pragma unroll
  for (int h = 0; h < 16; ++h) {
    float v = acc[h];
#pragma unroll
    for (int off = 32; off; off >>= 1) v += __shfl_down(v, off);
    if (lane == 0) red[w * 16 + h] = v;
  }
  __syncthreads();
  if (tid < 16) {
    float s = red[tid] + red[16 + tid] + red[32 + tid] + red[48 + tid];
    int b = row >> 11, n = row & 2047;
    gates[((size_t)(b * NH + tid)) * NSEQ + n] = 1.f / (1.f + expf(-s));
  }
}

// in: f32 [K][C] row-major -> out: bf16 [C][K] row-major
__global__ __launch_bounds__(256) void transpose_cvt_kernel(const float* __restrict__ in,
                                                            __bf16* __restrict__ out,
                                                            int K, int C) {
  __shared__ float tile[32][33];
  int c0 = blockIdx.x * 32, k0 = blockIdx.y * 32;
  int t = threadIdx.x;
  int lc = t & 31, lr = t >> 5;
#pragma unroll
  for (int rr = 0; rr < 4; ++rr)
    tile[lr + rr * 8][lc] = in[(size_t)(k0 + lr + rr * 8) * C + c0 + lc];
  __syncthreads();
#pragma unroll
  for (int rr = 0; rr < 4; ++rr)
    out[(size_t)(c0 + lr + rr * 8) * K + k0 + lc] = (__bf16)tile[lc][lr + rr * 8];
}

// ---------------------------------------------------------------------------
// qkv core: BM=256, BN=384, BK=32, 8 waves, LDS ring-of-3 (120KB), 2-phase
// MFMA split. Entry invariant at iter t: tiles <= t landed block-wide,
// tile t+1 in flight (5 loads), tile t+2 unissued.
//   P0: read 6 B-frags + af[0..3] of tile t | stage chunks 0-2 of t+2 |
//       barrier | setprio 24 MFMA | barrier
//   P1: read af[4..7] | stage chunks 3-4 of t+2 | barrier | setprio 24 MFMA |
//       vmcnt(5) [outstanding {t+1:5, t+2:5} -> retires exactly tile t+1] |
//       barrier
// Overwrite: stage at t targets slot (t-1)%3 whose readers' MFMAs (and thus
// lgkm-retired ds_reads) precede iter t-1's final barrier.
struct SmemQ {
  __bf16 T[3][640][32];  // 120 KiB
};

static __device__ __forceinline__ const bf16x8* fragq(const __bf16* base, int row, int g) {
  return (const bf16x8*)(base + row * 32 + (g ^ ((row >> 1) & 3)) * 8);
}

__global__ __launch_bounds__(512, 2) void gemm_qkv2p(const __bf16* __restrict__ A,
                                                     const __bf16* __restrict__ Bt,
                                                     __bf16* __restrict__ qb,
                                                     __bf16* __restrict__ kb,
                                                     __bf16* __restrict__ vtb) {
  __shared__ __align__(1024) SmemQ S;
  int sblk = blockIdx.x;
  int x = sblk & 7, i = sblk >> 3;
  int m0 = (i >> 1) * 256;
  int n0 = (2 * x + (i & 1)) * 384;   // XCD n-band (3.1MB B-band, L2-fit)
  const __bf16* Ab = A + (size_t)m0 * 2048;
  const __bf16* Bb = Bt + (size_t)n0 * 2048;

  int tid = threadIdx.x;
  int w = tid >> 6, lane = tid & 63;
  int ln15 = lane & 15, g = lane >> 4;
  int wr = w >> 2, wc = w & 3;
  int lr4 = lane >> 2, l3 = lane & 3;

  // stage chunk j (1KB = 16 rows) of K-tile kt into ring slot rb.
  auto stage1 = [&](int kt, int rb, int j) {
    int k = w + 8 * j;                 // chunk id 0..39 (k<16 -> A)
    int row = k * 16 + lr4;
    int sg = l3 ^ ((row >> 1) & 3);
    const __bf16* src = (k < 16)
        ? Ab + (size_t)row * 2048 + kt * 32 + sg * 8
        : Bb + (size_t)(row - 256) * 2048 + kt * 32 + sg * 8;
    gload_lds16(src, &S.T[rb][k * 16][0]);
  };
  auto stage_all = [&](int kt, int rb) {
#pragma unroll
    for (int j = 0; j < 5; ++j) stage1(kt, rb, j);
  };

  f32x4 acc[8][6];
#pragma unroll
  for (int a = 0; a < 8; ++a)
#pragma unroll
    for (int nf = 0; nf < 6; ++nf) acc[a][nf] = (f32x4){0.f, 0.f, 0.f, 0.f};

  stage_all(0, 0);
  stage_all(1, 1);
  // RACE FIX (R15 nan): tile 0 must be landed block-wide before iter 0 reads.
  asm volatile("s_waitcnt vmcnt(5)" ::: "memory");
  __builtin_amdgcn_s_barrier();
  for (int t = 0; t < 64; ++t) {
    int rb = t % 3;
    int ts = (t < 62) ? t + 2 : 63;
    int sb = (t + 2) % 3;
    const __bf16* Sb = &S.T[rb][0][0];
    bf16x8 bfr[6], af[4];
    // ---------------- P0: B-frags + af[0..3], 24 MFMA ----------------
#pragma unroll
    for (int nf = 0; nf < 6; ++nf) {
      int row = 256 + wc * 96 + nf * 16 + ln15;
      bfr[nf] = *fragq(Sb, row, g);
    }
#pragma unroll
    for (int a = 0; a < 4; ++a) {
      int row = wr * 128 + a * 16 + ln15;
      af[a] = *fragq(Sb, row, g);
    }
    stage1(ts, sb, 0); stage1(ts, sb, 1); stage1(ts, sb, 2);
    __builtin_amdgcn_s_barrier();
    __builtin_amdgcn_s_setprio(1);
#pragma unroll
    for (int a = 0; a < 4; ++a)
#pragma unroll
      for (int nf = 0; nf < 6; ++nf)
        acc[a][nf] = MFMA_BF16(af[a], bfr[nf], acc[a][nf]);
    __builtin_amdgcn_s_setprio(0);
    __builtin_amdgcn_s_barrier();
    // ---------------- P1: af[4..7], 24 MFMA, vmcnt ----------------
#pragma unroll
    for (int a = 0; a < 4; ++a) {
      int row = wr * 128 + (a + 4) * 16 + ln15;
      af[a] = *fragq(Sb, row, g);
    }
    stage1(ts, sb, 3); stage1(ts, sb, 4);
    __builtin_amdgcn_s_barrier();
    __builtin_amdgcn_s_setprio(1);
#pragma unroll
    for (int a = 0; a < 4; ++a)
#pragma unroll
      for (int nf = 0; nf < 6; ++nf)
        acc[a + 4][nf] = MFMA_BF16(af[a], bfr[nf], acc[a + 4][nf]);
    __builtin_amdgcn_s_setprio(0);
    // RACE FIX: outstanding = {t+1:5, t+2:5}; vmcnt(5) retires exactly t+1.
    asm volatile("s_waitcnt vmcnt(5)" ::: "memory");
    __builtin_amdgcn_s_barrier();
  }
  asm volatile("s_waitcnt vmcnt(0)" ::: "memory");  // drain tail junk

#pragma unroll
  for (int nf = 0; nf < 6; ++nf) {
    int ng = n0 + wc * 96 + nf * 16 + ln15;
    int qkv = ng >> 11;
    int h = (ng >> 7) & 15;
    int d = ng & 127;
#pragma unroll
    for (int mf = 0; mf < 8; ++mf)
#pragma unroll
      for (int rr = 0; rr < 4; ++rr) {
        int m = m0 + wr * 128 + mf * 16 + g * 4 + rr;
        int b = m >> 11, n = m & 2047;
        int bh = b * NH + h;
        float v = acc[mf][nf][rr];
        if (qkv == 0)
          qb[((size_t)bh * NSEQ + n) * NDH + d] = (__bf16)(v * SCALE_Q);
        else if (qkv == 1)
          kb[((size_t)bh * NSEQ + n) * NDH + d] = (__bf16)v;
        else
          vtb[((size_t)bh * NDH + d) * NSEQ + n] = (__bf16)v;
      }
  }
}

// ---------------------------------------------------------------------------
// gemm_out (unchanged R12): BM=256, BN=128, BK=32, ring-of-6, vmcnt(12),
// wait at TOP of iteration before reads (correct ledger, measured OK).
struct SmemO {
  __bf16 T[6][384][32];  // 144 KiB
};

__global__ __launch_bounds__(512, 2) void gemm_out256r(const __bf16* __restrict__ A,
                                                       const __bf16* __restrict__ Bt,
                                                       float* __restrict__ out) {
  __shared__ __align__(1024) SmemO S;
  int sblk = blockIdx.x;
  int x = sblk & 7, i = sblk >> 3;
  int m0 = (i >> 1) * 256;
  int n0 = (2 * x + (i & 1)) * 128;
  const __bf16* Ab = A + (size_t)m0 * 2048;
  const __bf16* Bb = Bt + (size_t)n0 * 2048;

  int tid = threadIdx.x;
  int w = tid >> 6, lane = tid & 63;
  int ln15 = lane & 15, g = lane >> 4;
  int wr = w >> 2, wc = w & 3;
  int lr4 = lane >> 2, l3 = lane & 3;

  auto stage = [&](int kt, int rb) {
#pragma unroll
    for (int j = 0; j < 3; ++j) {
      int k = w + 8 * j;
      int row = k * 16 + lr4;
      int sg = l3 ^ ((row >> 1) & 3);
      const __bf16* src = (k < 16)
          ? Ab + (size_t)row * 2048 + kt * 32 + sg * 8
          : Bb + (size_t)(row - 256) * 2048 + kt * 32 + sg * 8;
      gload_lds16(src, &S.T[rb][k * 16][0]);
    }
  };

  f32x4 acc[8][2];
#pragma unroll
  for (int a = 0; a < 8; ++a)
#pragma unroll
    for (int nf = 0; nf < 2; ++nf) acc[a][nf] = (f32x4){0.f, 0.f, 0.f, 0.f};

  stage(0, 0); stage(1, 1); stage(2, 2); stage(3, 3); stage(4, 4);
  for (int t = 0; t < 64; ++t) {
    int rb = t % 6;
    asm volatile("s_waitcnt vmcnt(12)" ::: "memory");
    __builtin_amdgcn_s_barrier();
    asm volatile("" ::: "memory");
    int ts = (t < 59) ? t + 5 : 63;
    stage(ts, (t + 5) % 6);
    const __bf16* Sb = &S.T[rb][0][0];
    bf16x8 bfr[2];
#pragma unroll
    for (int nf = 0; nf < 2; ++nf) {
      int row = 256 + wc * 32 + nf * 16 + ln15;
      bfr[nf] = *fragq(Sb, row, g);
    }
#pragma unroll
    for (int mh = 0; mh < 2; ++mh) {
      bf16x8 af[4];
#pragma unroll
      for (int a = 0; a < 4; ++a) {
        int row = wr * 128 + (mh * 4 + a) * 16 + ln15;
        af[a] = *fragq(Sb, row, g);
      }
      __builtin_amdgcn_s_setprio(1);
#pragma unroll
      for (int a = 0; a < 4; ++a)
#pragma unroll
        for (int nf = 0; nf < 2; ++nf)
          acc[mh * 4 + a][nf] = MFMA_BF16(af[a], bfr[nf], acc[mh * 4 + a][nf]);
      __builtin_amdgcn_s_setprio(0);
    }
  }
  asm volatile("s_waitcnt vmcnt(0)" ::: "memory");

#pragma unroll
  for (int mf = 0; mf < 8; ++mf)
#pragma unroll
    for (int nf = 0; nf < 2; ++nf)
#pragma unroll
      for (int rr = 0; rr < 4; ++rr) {
        int m = m0 + wr * 128 + mf * 16 + g * 4 + rr;
        int c = n0 + wc * 32 + nf * 16 + ln15;
        out[(size_t)m * NDIM + c] = acc[mf][nf][rr];
      }
}

// ---------------------------------------------------------------------------
// Flash attention (unchanged R11/R12): 256 thr / 4 waves, dual-q (lo,31-lo),
// 512 blocks = 2/CU, dbuf KV + counted vmcnt(8), fixed-max softmax, fused softcap.
static __device__ __forceinline__ void softcap_p(const f32x4* accS, float (*p)[4],
                                                 float& l_r, int j0, int q0s,
                                                 bool diag, int ln15, int g) {
#pragma unroll
  for (int jt = 0; jt < 4; ++jt)
#pragma unroll
    for (int r = 0; r < 4; ++r) {
      float e2 = __builtin_amdgcn_exp2f(accS[jt][r] * 0.057707801635558536f);
      float rc = __builtin_amdgcn_rcpf(e2 + 1.f);
      float pv = __builtin_amdgcn_exp2f(fmaf(rc, -144.26950408889634f, 54.82241155378061f));
      if (diag && (j0 + jt * 16 + g * 4 + r > q0s + ln15)) pv = 0.f;
      p[jt][r] = pv;
      l_r += pv;
    }
}

static __device__ __forceinline__ bf16x8 build_pa(const float (*p)[4], int c,
                                                  int lane_lo, int lane_hi, int g) {
  unsigned P0w0 = pack2_bf16(p[2 * c][0], p[2 * c][1]);
  unsigned P0w1 = pack2_bf16(p[2 * c][2], p[2 * c][3]);
  unsigned P1w0 = pack2_bf16(p[2 * c + 1][0], p[2 * c + 1][1]);
  unsigned P1w1 = pack2_bf16(p[2 * c + 1][2], p[2 * c + 1][3]);
  unsigned a0 = (unsigned)__shfl((int)P0w0, lane_lo);
  unsigned a1 = (unsigned)__shfl((int)P0w1, lane_lo);
  unsigned b0 = (unsigned)__shfl((int)P1w0, lane_lo);
  unsigned b1 = (unsigned)__shfl((int)P1w1, lane_lo);
  unsigned c0 = (unsigned)__shfl((int)P0w0, lane_hi);
  unsigned c1 = (unsigned)__shfl((int)P0w1, lane_hi);
  unsigned e0 = (unsigned)__shfl((int)P1w0, lane_hi);
  unsigned e1 = (unsigned)__shfl((int)P1w1, lane_hi);
  union { unsigned u[4]; bf16x8 v; } pu;
  pu.u[0] = (g < 2) ? a0 : b0;
  pu.u[1] = (g < 2) ? a1 : b1;
  pu.u[2] = (g < 2) ? c0 : e0;
  pu.u[3] = (g < 2) ? c1 : e1;
  return pu.v;
}

static __device__ __forceinline__ void attn_tile2(const __bf16* __restrict__ Kl,
                                                  const __bf16* __restrict__ Vl,
                                                  const bf16x8* qfh, const bf16x8* qfl,
                                                  f32x4* acc_h, f32x4* acc_l,
                                                  float& l_h, float& l_l,
                                                  int j0, int q0h, int q0l,
                                                  bool diag_h, bool diag_l, bool do_lo,
                                                  int ln15, int g) {
  f32x4 sh[4], sl[4];
#pragma unroll
  for (int jt = 0; jt < 4; ++jt) {
    sh[jt] = (f32x4){0.f, 0.f, 0.f, 0.f};
    sl[jt] = (f32x4){0.f, 0.f, 0.f, 0.f};
  }
  __builtin_amdgcn_s_setprio(1);
#pragma unroll
  for (int jt = 0; jt < 4; ++jt)
#pragma unroll
    for (int kc = 0; kc < 4; ++kc) {
      int row = jt * 16 + ln15;
      int bc = (kc * 64 + g * 16) ^ ((row & 7) << 4);
      bf16x8 kf = *reinterpret_cast<const bf16x8*>(Kl + row * 128 + (bc >> 1));
      sh[jt] = MFMA_BF16(kf, qfh[kc], sh[jt]);
      if (do_lo) sl[jt] = MFMA_BF16(kf, qfl[kc], sl[jt]);
    }
  __builtin_amdgcn_s_setprio(0);
  float ph[4][4], pl[4][4];
  softcap_p(sh, ph, l_h, j0, q0h, diag_h, ln15, g);
  if (do_lo) softcap_p(sl, pl, l_l, j0, q0l, diag_l, ln15, g);
  int lane_lo = ln15 + 32 * (g & 1);
  int lane_hi = lane_lo + 16;
#pragma unroll
  for (int c = 0; c < 2; ++c) {
    bf16x8 pah = build_pa(ph, c, lane_lo, lane_hi, g);
    bf16x8 pal = build_pa(pl, c, lane_lo, lane_hi, g);
    __builtin_amdgcn_s_setprio(1);
#pragma unroll
    for (int d0 = 0; d0 < 8; ++d0) {
      int d = d0 * 16 + ln15;
      int bc = (c * 64 + g * 16) ^ ((d & 7) << 4);
      bf16x8 vf = *reinterpret_cast<const bf16x8*>(Vl + d * 64 + (bc >> 1));
      acc_h[d0] = MFMA_BF16(pah, vf, acc_h[d0]);
      if (do_lo) acc_l[d0] = MFMA_BF16(pal, vf, acc_l[d0]);
    }
    __builtin_amdgcn_s_setprio(0);
  }
}

__global__ __launch_bounds__(256, 2) void attn_kernel(const __bf16* __restrict__ qb,
                                                      const __bf16* __restrict__ kb,
                                                      const __bf16* __restrict__ vtb,
                                                      const float* __restrict__ gates,
                                                      __bf16* __restrict__ og) {
  __shared__ __align__(1024) __bf16 Kl[2][64 * 128];
  __shared__ __align__(1024) __bf16 Vl[2][128 * 64];
  int tid = threadIdx.x;
  int w = tid >> 6, lane = tid & 63;
  int ln15 = lane & 15, g = lane >> 4;
  int bx = blockIdx.x;
  int lo = bx & 15, bh = bx >> 4;
  int hi = 31 - lo;
  const __bf16* qh = qb + (size_t)bh * NSEQ * NDH;
  const __bf16* kh = kb + (size_t)bh * NSEQ * NDH;
  const __bf16* vh = vtb + (size_t)bh * NDH * NSEQ;

  int q0h = hi * 64 + w * 16;
  int q0l = lo * 64 + w * 16;
  bf16x8 qfh[4], qfl[4];
#pragma unroll
  for (int kc = 0; kc < 4; ++kc) {
    qfh[kc] = *reinterpret_cast<const bf16x8*>(qh + (size_t)(q0h + ln15) * NDH + kc * 32 + g * 8);
    qfl[kc] = *reinterpret_cast<const bf16x8*>(qh + (size_t)(q0l + ln15) * NDH + kc * 32 + g * 8);
  }

  f32x4 acc_h[8], acc_l[8];
#pragma unroll
  for (int d0 = 0; d0 < 8; ++d0) {
    acc_h[d0] = (f32x4){0.f, 0.f, 0.f, 0.f};
    acc_l[d0] = (f32x4){0.f, 0.f, 0.f, 0.f};
  }
  float l_h = 0.f, l_l = 0.f;

  auto stage = [&](int t, int buf) {
    int j0 = t * 64;
#pragma unroll
    for (int i = 0; i < 4; ++i) {
      int gi = (i * 4 + w) * 64 + lane;
      int kr = gi >> 4, kcs = gi & 15;
      int kc_ = kcs ^ (kr & 7);
      gload_lds16(kh + (size_t)(j0 + kr) * NDH + kc_ * 8, &Kl[buf][(i * 4 + w) * 512]);
      int vr = gi >> 3, vcs = gi & 7;
      int vc_ = vcs ^ (vr & 7);
      gload_lds16(vh + (size_t)vr * NSEQ + j0 + vc_ * 8, &Vl[buf][(i * 4 + w) * 512]);
    }
  };

  stage(0, 0);
  for (int t = 0; t <= hi; ++t) {
    int cb = t & 1;
    if (t < hi) {
      stage(t + 1, cb ^ 1);
      asm volatile("s_waitcnt vmcnt(8)" ::: "memory");
    } else {
      asm volatile("s_waitcnt vmcnt(0)" ::: "memory");
    }
    __builtin_amdgcn_s_barrier();
    attn_tile2(&Kl[cb][0], &Vl[cb][0], qfh, qfl, acc_h, acc_l, l_h, l_l,
               t * 64, q0h, q0l, t == hi, t == lo, t <= lo, ln15, g);
    __builtin_amdgcn_s_barrier();
  }

  l_h += __shfl_xor(l_h, 16); l_h += __shfl_xor(l_h, 32);
  l_l += __shfl_xor(l_l, 16); l_l += __shfl_xor(l_l, 32);

  int b = bh >> 4, h = bh & 15;
#pragma unroll
  for (int set = 0; set < 2; ++set) {
    int q0s = set ? q0l : q0h;
    f32x4* acc = set ? acc_l : acc_h;
    float lr = set ? l_l : l_h;
    float gv[4];
#pragma unroll
    for (int r = 0; r < 4; ++r) {
      float lv = __shfl(lr, g * 4 + r);
      int row = q0s + g * 4 + r;
      gv[r] = gates[(size_t)bh * NSEQ + row] / lv;
    }
#pragma unroll
    for (int d0 = 0; d0 < 8; ++d0)
#pragma unroll
      for (int r = 0; r < 4; ++r) {
        int row = q0s + g * 4 + r;
        og[((size_t)(b * NSEQ + row)) * NDIM + h * NDH + d0 * 16 + ln15] =
            (__bf16)(acc[d0][r] * gv[r]);
      }
  }
}

// ---------------------------------------------------------------------------
extern "C" void kernel_launch(void* const* d_in, const int* in_sizes, int n_in,
                              void* d_out, int out_size, void* d_ws, size_t ws_size,
                              hipStream_t stream) {
  const float* x = (const float*)d_in[0];
  const float* w_qkv = (const float*)d_in[1];
  const float* w_gates = (const float*)d_in[2];
  const float* w_out = (const float*)d_in[3];
  float* out = (float*)d_out;
  char* ws = (char*)d_ws;

  __bf16* x_bf   = (__bf16*)(ws + 0);          // 16,777,216
  __bf16* wqkv_t = (__bf16*)(ws + 16777216);   // 25,165,824
  __bf16* wout_t = (__bf16*)(ws + 41943040);   // 8,388,608
  __bf16* q_buf  = (__bf16*)(ws + 50331648);   // 16,777,216
  __bf16* k_buf  = (__bf16*)(ws + 67108864);   // 16,777,216
  __bf16* vt_buf = (__bf16*)(ws + 83886080);   // 16,777,216
  float*  gates  = (float*)(ws + 100663296);   // 262,144
  __bf16* attn_g = (__bf16*)(ws + 100925440);  // 16,777,216

  cvt_gates_kernel<<<4096, 256, 0, stream>>>(x, w_gates, x_bf, gates);
  transpose_cvt_kernel<<<dim3(192, 64), 256, 0, stream>>>(w_qkv, wqkv_t, 2048, 6144);
  transpose_cvt_kernel<<<dim3(64, 64), 256, 0, stream>>>(w_out, wout_t, 2048, 2048);
  gemm_qkv2p<<<256, 512, 0, stream>>>(x_bf, wqkv_t, q_buf, k_buf, vt_buf);
  attn_kernel<<<512, 256, 0, stream>>>(q_buf, k_buf, vt_buf, gates, attn_g);
  gemm_out256r<<<256, 512, 0, stream>>>(attn_g, wout_t, out);
}